// Round 3
// baseline (1381.147 us; speedup 1.0000x reference)
//
#include <hip/hip_runtime.h>

// Problem dims (fixed)
#define HID_   128
#define BB_    256
#define TT_    300
#define DIN_   700
#define LL_    4
#define NOUT_  20
#define NROWS_ (BB_*TT_)          // 76800

// d_out layout (floats): out[256*20] | hid4_mem[256*301*128] | hid4_spk[...] | A_norm[1]
#define OUT_OFF   0
#define HMEM_OFF  5120
#define HSPK_OFF  (5120 + 256*301*128)            // 9,868,288
#define ANORM_OFF (5120 + 2*256*301*128)          // 19,731,456

// ---------------------------------------------------------------------------
// K1: inp[r][h] = sum_d x[r][d] * w_in[d][h] + b_in[h]
// 128 threads (h), 16 rows/block, K chunked by 28 (700 = 25*28).
// launch_bounds(128,2): VGPR budget ~128 (empirical: budget ~= 256/min_waves;
// (128,8) squeezed to 32 regs and spilled 1.3 GB of scratch to HBM in R2).
// acc[16]+wreg[28]+temps ~= 70 regs -> register tile survives.
// ---------------------------------------------------------------------------
__global__ __launch_bounds__(128, 2)
void k1_in_proj(const float* __restrict__ x, const float* __restrict__ w,
                const float* __restrict__ bin, float* __restrict__ inp)
{
    const int h = threadIdx.x;
    const long r0 = (long)blockIdx.x * 16;

    float acc[16];
    const float bv = bin[h];
#pragma unroll
    for (int r = 0; r < 16; ++r) acc[r] = bv;

    for (int kc = 0; kc < 25; ++kc) {
        const int k0 = kc * 28;
        float wreg[28];
#pragma unroll
        for (int j = 0; j < 28; ++j) wreg[j] = w[(long)(k0 + j) * 128 + h];

#pragma unroll
        for (int r = 0; r < 16; ++r) {
            const float* __restrict__ xr = x + (r0 + r) * (long)DIN_ + k0;
#pragma unroll
            for (int j = 0; j < 28; ++j)
                acc[r] = fmaf(xr[j], wreg[j], acc[r]);
        }
    }

#pragma unroll
    for (int r = 0; r < 16; ++r)
        inp[(r0 + r) * (long)HID_ + h] = acc[r];
}

// ---------------------------------------------------------------------------
// K2: drive GEMM  xs[l][r][h] = sum_k inp[r][k] * A_w[l][k][h] + A_b[l][h]
// Same register-tile structure; launch_bounds(128,2) to avoid the R2 spill.
// ---------------------------------------------------------------------------
__global__ __launch_bounds__(128, 2)
void k2_drive(const float* __restrict__ inp, const float* __restrict__ Aw,
              const float* __restrict__ Ab, float* __restrict__ xs,
              int lsel, long lstride)
{
    const int h = threadIdx.x;
    int l, tile;
    if (lsel >= 0) { l = lsel; tile = blockIdx.x; }
    else           { l = blockIdx.x & 3; tile = blockIdx.x >> 2; }
    const long r0 = (long)tile * 16;
    const float* __restrict__ A = Aw + (long)l * 128 * 128;

    float acc[16];
    const float bv = Ab[l * 128 + h];
#pragma unroll
    for (int r = 0; r < 16; ++r) acc[r] = bv;

#pragma unroll
    for (int kc = 0; kc < 4; ++kc) {
        const int k0 = kc * 32;
        float wreg[32];
#pragma unroll
        for (int j = 0; j < 32; ++j) wreg[j] = A[(long)(k0 + j) * 128 + h];

#pragma unroll
        for (int r = 0; r < 16; ++r) {
            const float* __restrict__ xr = inp + (r0 + r) * (long)HID_ + k0;
#pragma unroll
            for (int j = 0; j < 32; ++j)
                acc[r] = fmaf(xr[j], wreg[j], acc[r]);
        }
    }

    float* __restrict__ op = xs + ((long)l * lstride + r0) * HID_ + h;
#pragma unroll
    for (int r = 0; r < 16; ++r)
        op[(long)r * HID_] = acc[r];
}

// ---------------------------------------------------------------------------
// K3': elementwise scan over t. thread = (l,b,h). 20 loads in flight/iter
// (300 = 15*20); launch_bounds(128,4) -> ~64-reg budget, v[20]+temps fits.
// ---------------------------------------------------------------------------
__global__ __launch_bounds__(128, 4)
void k3_scan_split(const float* __restrict__ xs, const float* __restrict__ thr,
                   const float* __restrict__ dec, const float* __restrict__ rstv,
                   const float* __restrict__ mem0, float* __restrict__ rates,
                   float* __restrict__ omem, float* __restrict__ ospk,
                   int lsel, long lstride)
{
    const int h = threadIdx.x;
    int l, b;
    if (lsel >= 0) { l = lsel; b = blockIdx.x; }
    else           { l = blockIdx.x >> 8; b = blockIdx.x & 255; }

    const float th = thr[h];
    const float dc = dec[h];
    const float rs = rstv[h];

    float mem = mem0[((long)l * 256 + b) * 128 + h];
    float spk = 0.f;
    float cnt = 0.f;

    const bool last = (l == 3);
    float* __restrict__ om = omem + (long)b * 301 * 128 + h;
    float* __restrict__ os = ospk + (long)b * 301 * 128 + h;
    if (last) { om[0] = mem; os[0] = 0.f; }

    const float* __restrict__ p = xs + ((long)l * lstride + (long)b * TT_) * HID_ + h;

    for (int t0 = 0; t0 < TT_; t0 += 20) {
        float v[20];
#pragma unroll
        for (int j = 0; j < 20; ++j) v[j] = p[(long)(t0 + j) * HID_];
#pragma unroll
        for (int j = 0; j < 20; ++j) {
            mem = rs * spk + mem * dc * (1.f - spk) + v[j];
            spk = (mem - th > 0.f) ? 1.f : 0.f;
            cnt += spk;
            if (last) {
                om[(long)(t0 + j + 1) * 128] = mem;
                os[(long)(t0 + j + 1) * 128] = spk;
            }
        }
    }

    rates[((long)l * 256 + b) * 128 + h] = cnt * (1.f / 300.f);
}

// ---------------------------------------------------------------------------
// Legacy fused drive+scan (fallback when ws is tiny).
// ---------------------------------------------------------------------------
__global__ __launch_bounds__(128, 2)
void k3_fused(const float* __restrict__ inp, const float* __restrict__ Aw,
              const float* __restrict__ Ab, const float* __restrict__ thr,
              const float* __restrict__ dec, const float* __restrict__ rstv,
              const float* __restrict__ mem0, float* __restrict__ rates,
              float* __restrict__ omem, float* __restrict__ ospk)
{
    const int h = threadIdx.x;
    const int bid = blockIdx.x;
    const int l = bid & 3;
    const int b = bid >> 2;

    float a[128];
#pragma unroll
    for (int k = 0; k < 128; ++k)
        a[k] = Aw[((long)l * 128 + k) * 128 + h];

    const float ab = Ab[l * 128 + h];
    const float th = thr[h];
    const float dc = dec[h];
    const float rs = rstv[h];

    float mem = mem0[((long)l * 256 + b) * 128 + h];
    float spk = 0.f;
    float cnt = 0.f;

    const bool last = (l == 3);
    float* __restrict__ om = omem + (long)b * 301 * 128 + h;
    float* __restrict__ os = ospk + (long)b * 301 * 128 + h;
    if (last) { om[0] = mem; os[0] = 0.f; }

    const float* __restrict__ ip = inp + (long)b * 300 * 128;

    for (int t = 0; t < 300; ++t) {
        float acc = ab;
#pragma unroll
        for (int k = 0; k < 128; ++k)
            acc = fmaf(ip[k], a[k], acc);
        ip += 128;

        mem = rs * spk + mem * dc * (1.f - spk) + acc;
        spk = (mem - th > 0.f) ? 1.f : 0.f;
        cnt += spk;

        if (last) {
            om[(long)(t + 1) * 128] = mem;
            os[(long)(t + 1) * 128] = spk;
        }
    }

    rates[((long)l * 256 + b) * 128 + h] = cnt * (1.f / 300.f);
}

// ---------------------------------------------------------------------------
// K4: head. block per batch row b.
// ---------------------------------------------------------------------------
__global__ __launch_bounds__(256)
void k4_head(const float* __restrict__ rates, const float* __restrict__ fcw,
             const float* __restrict__ fcb, const float* __restrict__ wout,
             const float* __restrict__ bout, float* __restrict__ out)
{
    __shared__ float cat[512];
    const int b = blockIdx.x;
    const int tid = threadIdx.x;

    for (int c = tid; c < 512; c += 256) {
        const int l = c >> 7;
        const int k = c & 127;
        float s = fcb[l * 128 + k];
        const float* __restrict__ rp = rates + ((long)l * 256 + b) * 128;
        const float* __restrict__ wp = fcw + (long)l * 128 * 128 + k;
#pragma unroll 8
        for (int hh = 0; hh < 128; ++hh)
            s = fmaf(rp[hh], wp[(long)hh * 128], s);
        cat[c] = s > 0.f ? s : 0.f;
    }
    __syncthreads();

    if (tid < NOUT_) {
        float s = bout[tid];
#pragma unroll 8
        for (int c = 0; c < 512; ++c)
            s = fmaf(cat[c], wout[(long)c * NOUT_ + tid], s);
        out[(long)b * NOUT_ + tid] = s;
    }
}

// ---------------------------------------------------------------------------
// K5: A_norm = sum |A_w|. Single block.
// ---------------------------------------------------------------------------
__global__ __launch_bounds__(256)
void k5_anorm(const float* __restrict__ Aw, float* __restrict__ out)
{
    __shared__ float red[256];
    const int tid = threadIdx.x;
    float s = 0.f;
    for (int i = tid; i < LL_ * 128 * 128; i += 256)
        s += fabsf(Aw[i]);
    red[tid] = s;
    __syncthreads();
#pragma unroll
    for (int st = 128; st > 0; st >>= 1) {
        if (tid < st) red[tid] += red[tid + st];
        __syncthreads();
    }
    if (tid == 0) out[0] = red[0];
}

// ---------------------------------------------------------------------------
extern "C" void kernel_launch(void* const* d_in, const int* in_sizes, int n_in,
                              void* d_out, int out_size, void* d_ws, size_t ws_size,
                              hipStream_t stream)
{
    const float* x    = (const float*)d_in[0];
    const float* w_in = (const float*)d_in[1];
    const float* b_in = (const float*)d_in[2];
    const float* A_w  = (const float*)d_in[3];
    const float* A_b  = (const float*)d_in[4];
    const float* fc_w = (const float*)d_in[5];
    const float* fc_b = (const float*)d_in[6];
    const float* w_out= (const float*)d_in[7];
    const float* b_out= (const float*)d_in[8];
    const float* thr  = (const float*)d_in[9];
    const float* dec  = (const float*)d_in[10];
    const float* rst  = (const float*)d_in[11];
    const float* mem0 = (const float*)d_in[12];

    float* out = (float*)d_out;
    float* ws  = (float*)d_ws;

    const long INP_ELTS = (long)NROWS_ * HID_;        //  9,830,400
    const long XS_FULL  = 4L * NROWS_ * HID_;         // 39,321,600
    const long RATES    = 4L * 256 * 128;

    float* inp = ws;                                   // always first

    // K1: input projection. 76800/16 = 4800 blocks.
    k1_in_proj<<<4800, 128, 0, stream>>>(x, w_in, b_in, inp);

    const size_t need_full = (size_t)(INP_ELTS + XS_FULL + RATES) * 4;
    const size_t need_perl = (size_t)(INP_ELTS + INP_ELTS + RATES) * 4;

    if (ws_size >= need_full) {
        float* xs    = ws + INP_ELTS;
        float* rates = xs + XS_FULL;
        k2_drive<<<19200, 128, 0, stream>>>(inp, A_w, A_b, xs, -1, (long)NROWS_);
        k3_scan_split<<<1024, 128, 0, stream>>>(xs, thr, dec, rst, mem0, rates,
                                                out + HMEM_OFF, out + HSPK_OFF,
                                                -1, (long)NROWS_);
        k4_head<<<256, 256, 0, stream>>>(rates, fc_w, fc_b, w_out, b_out, out + OUT_OFF);
    } else if (ws_size >= need_perl) {
        float* xs    = ws + INP_ELTS;
        float* rates = xs + INP_ELTS;
        for (int l = 0; l < 4; ++l) {
            k2_drive<<<4800, 128, 0, stream>>>(inp, A_w, A_b, xs, l, 0L);
            k3_scan_split<<<256, 128, 0, stream>>>(xs, thr, dec, rst, mem0, rates,
                                                   out + HMEM_OFF, out + HSPK_OFF,
                                                   l, 0L);
        }
        k4_head<<<256, 256, 0, stream>>>(rates, fc_w, fc_b, w_out, b_out, out + OUT_OFF);
    } else {
        float* rates = ws + INP_ELTS;
        k3_fused<<<1024, 128, 0, stream>>>(inp, A_w, A_b, thr, dec, rst, mem0,
                                           rates, out + HMEM_OFF, out + HSPK_OFF);
        k4_head<<<256, 256, 0, stream>>>(rates, fc_w, fc_b, w_out, b_out, out + OUT_OFF);
    }

    // K5: A_norm (independent)
    k5_anorm<<<1, 256, 0, stream>>>(A_w, out + ANORM_OFF);
}

// Round 4
// 755.742 us; speedup vs baseline: 1.8275x; 1.8275x over previous
//
#include <hip/hip_runtime.h>

// Problem dims (fixed)
#define HID_   128
#define BB_    256
#define TT_    300
#define DIN_   700
#define LL_    4
#define NOUT_  20
#define NROWS_ (BB_*TT_)          // 76800

// d_out layout (floats): out[256*20] | hid4_mem[256*301*128] | hid4_spk[...] | A_norm[1]
#define OUT_OFF   0
#define HMEM_OFF  5120
#define HSPK_OFF  (5120 + 256*301*128)
#define ANORM_OFF (5120 + 2*256*301*128)

typedef __attribute__((ext_vector_type(8))) short  bfrag;   // 8 bf16 (4 VGPR)
typedef __attribute__((ext_vector_type(4))) float  f32x4;   // MFMA C/D

// f32 -> bf16 (RNE) bit helpers
__device__ __forceinline__ unsigned short f2bf(float f) {
    unsigned int u = __float_as_uint(f);
    return (unsigned short)((u + 0x7fffu + ((u >> 16) & 1u)) >> 16);
}
__device__ __forceinline__ float bf2f(unsigned short h) {
    return __uint_as_float(((unsigned int)h) << 16);
}
__device__ __forceinline__ void split2(float v, unsigned short& hi, unsigned short& lo) {
    hi = f2bf(v);
    lo = f2bf(v - bf2f(hi));
}

// ---------------------------------------------------------------------------
// K1 (MFMA): inp[r][h] = sum_d x[r][d]*w_in[d][h] + b_in[h]
// Block 256 thr = 4 waves; wave = 16 rows x 128 cols (8 n-tiles of 16x16x32).
// Split-bf16: 3 MFMAs per tile-pair (hh, hl, lh) ~ f32 precision (err ~2^-18).
// W k-chunk staged in LDS pre-split hi/lo, layout [n][k] stride 40 (2-way max).
// ---------------------------------------------------------------------------
__global__ __launch_bounds__(256, 2)
void k1_mfma(const float* __restrict__ x, const float* __restrict__ w,
             const float* __restrict__ bin, float* __restrict__ inp)
{
    __shared__ unsigned short whi[128 * 40];
    __shared__ unsigned short wlo[128 * 40];

    const int tid  = threadIdx.x;
    const int wave = tid >> 6;
    const int lane = tid & 63;
    const int l15  = lane & 15;
    const int kg   = lane >> 4;          // 0..3
    const long m0  = (long)blockIdx.x * 64 + wave * 16;
    const long arow = m0 + l15;          // A row this lane loads

    f32x4 acc[8];
#pragma unroll
    for (int nt = 0; nt < 8; ++nt) {
        const float bv = bin[nt * 16 + l15];
        acc[nt] = (f32x4){bv, bv, bv, bv};
    }

    for (int ks = 0; ks < 22; ++ks) {
        const int k0 = ks * 32;
        // ---- stage w chunk [k0..k0+31] x 128, split hi/lo, [n][k] stride 40
        const int lim = (700 - k0) * 128;          // valid flat elems this chunk
        const float* __restrict__ wsrc = w + (long)k0 * 128;
#pragma unroll
        for (int j = 0; j < 16; ++j) {
            const int i = tid + j * 256;           // 0..4095
            const int kk = i >> 7, nn = i & 127;
            float v = (i < lim) ? wsrc[i] : 0.f;
            unsigned short hi, lo;
            split2(v, hi, lo);
            whi[nn * 40 + kk] = hi;
            wlo[nn * 40 + kk] = lo;
        }
        __syncthreads();

        // ---- A fragment: x[arow][k0 + kg*8 + j], split hi/lo
        bfrag ahi, alo;
        const int kbase = k0 + kg * 8;
        const float* __restrict__ xr = x + arow * (long)DIN_ + kbase;
        if (kbase + 7 < 700) {
            const float4 p0 = *(const float4*)(xr);
            const float4 p1 = *(const float4*)(xr + 4);
            float vv[8] = {p0.x, p0.y, p0.z, p0.w, p1.x, p1.y, p1.z, p1.w};
#pragma unroll
            for (int j = 0; j < 8; ++j) {
                unsigned short hi, lo; split2(vv[j], hi, lo);
                ahi[j] = (short)hi; alo[j] = (short)lo;
            }
        } else {
#pragma unroll
            for (int j = 0; j < 8; ++j) {
                float v = (kbase + j < 700) ? xr[j] : 0.f;
                unsigned short hi, lo; split2(v, hi, lo);
                ahi[j] = (short)hi; alo[j] = (short)lo;
            }
        }

        // ---- 8 n-tiles, 3 MFMAs each
#pragma unroll
        for (int nt = 0; nt < 8; ++nt) {
            const int boff = (nt * 16 + l15) * 40 + kg * 8;
            const bfrag bhi = *(const bfrag*)&whi[boff];
            const bfrag blo = *(const bfrag*)&wlo[boff];
            acc[nt] = __builtin_amdgcn_mfma_f32_16x16x32_bf16(ahi, bhi, acc[nt], 0, 0, 0);
            acc[nt] = __builtin_amdgcn_mfma_f32_16x16x32_bf16(ahi, blo, acc[nt], 0, 0, 0);
            acc[nt] = __builtin_amdgcn_mfma_f32_16x16x32_bf16(alo, bhi, acc[nt], 0, 0, 0);
        }
        __syncthreads();
    }

    // ---- epilogue: D row = kg*4 + reg, col = nt*16 + l15
#pragma unroll
    for (int nt = 0; nt < 8; ++nt) {
        const int col = nt * 16 + l15;
#pragma unroll
        for (int reg = 0; reg < 4; ++reg)
            inp[(m0 + kg * 4 + reg) * (long)HID_ + col] = acc[nt][reg];
    }
}

// ---------------------------------------------------------------------------
// K2 (MFMA): xs[l][r][h] = sum_k inp[r][k]*A_w[l][k][h] + A_b[l][h]
// Same wave structure; A_w staged in two 64-k chunks, [n][k] stride 72.
// lsel >= 0: that layer only, xs holds one layer (lbase=0).
// ---------------------------------------------------------------------------
__global__ __launch_bounds__(256, 2)
void k2_mfma(const float* __restrict__ inp, const float* __restrict__ Aw,
             const float* __restrict__ Ab, float* __restrict__ xs,
             int lsel, long lstride)
{
    __shared__ unsigned short ahiS[128 * 72];
    __shared__ unsigned short aloS[128 * 72];

    const int tid  = threadIdx.x;
    const int wave = tid >> 6;
    const int lane = tid & 63;
    const int l15  = lane & 15;
    const int kg   = lane >> 4;
    const int l    = (lsel >= 0) ? lsel : (int)blockIdx.y;
    const long m0  = (long)blockIdx.x * 64 + wave * 16;
    const long arow = m0 + l15;
    const long lbase = (lsel >= 0) ? 0 : (long)l * lstride;

    f32x4 acc[8];
#pragma unroll
    for (int nt = 0; nt < 8; ++nt) {
        const float bv = Ab[l * 128 + nt * 16 + l15];
        acc[nt] = (f32x4){bv, bv, bv, bv};
    }

    const float* __restrict__ Al = Aw + (long)l * 128 * 128;

    for (int kc = 0; kc < 2; ++kc) {
        // ---- stage A_w[l][kc*64 + k][n] -> planes [n][k] stride 72
        const float* __restrict__ asrc = Al + (long)kc * 64 * 128;
#pragma unroll
        for (int j = 0; j < 32; ++j) {
            const int i = tid + j * 256;           // 0..8191
            const int kk = i >> 7, nn = i & 127;
            unsigned short hi, lo;
            split2(asrc[i], hi, lo);
            ahiS[nn * 72 + kk] = hi;
            aloS[nn * 72 + kk] = lo;
        }
        __syncthreads();

#pragma unroll
        for (int ks = 0; ks < 2; ++ks) {
            const int k0 = kc * 64 + ks * 32;
            bfrag ahi, alo;
            const float* __restrict__ ir = inp + arow * (long)HID_ + k0 + kg * 8;
            const float4 p0 = *(const float4*)(ir);
            const float4 p1 = *(const float4*)(ir + 4);
            float vv[8] = {p0.x, p0.y, p0.z, p0.w, p1.x, p1.y, p1.z, p1.w};
#pragma unroll
            for (int j = 0; j < 8; ++j) {
                unsigned short hi, lo; split2(vv[j], hi, lo);
                ahi[j] = (short)hi; alo[j] = (short)lo;
            }

#pragma unroll
            for (int nt = 0; nt < 8; ++nt) {
                const int boff = (nt * 16 + l15) * 72 + ks * 32 + kg * 8;
                const bfrag bhi = *(const bfrag*)&ahiS[boff];
                const bfrag blo = *(const bfrag*)&aloS[boff];
                acc[nt] = __builtin_amdgcn_mfma_f32_16x16x32_bf16(ahi, bhi, acc[nt], 0, 0, 0);
                acc[nt] = __builtin_amdgcn_mfma_f32_16x16x32_bf16(ahi, blo, acc[nt], 0, 0, 0);
                acc[nt] = __builtin_amdgcn_mfma_f32_16x16x32_bf16(alo, bhi, acc[nt], 0, 0, 0);
            }
        }
        __syncthreads();
    }

#pragma unroll
    for (int nt = 0; nt < 8; ++nt) {
        const int col = nt * 16 + l15;
#pragma unroll
        for (int reg = 0; reg < 4; ++reg)
            xs[(lbase + m0 + kg * 4 + reg) * (long)HID_ + col] = acc[nt][reg];
    }
}

// ---------------------------------------------------------------------------
// K3': elementwise scan over t. 20 loads in flight per iter.
// ---------------------------------------------------------------------------
__global__ __launch_bounds__(128, 4)
void k3_scan_split(const float* __restrict__ xs, const float* __restrict__ thr,
                   const float* __restrict__ dec, const float* __restrict__ rstv,
                   const float* __restrict__ mem0, float* __restrict__ rates,
                   float* __restrict__ omem, float* __restrict__ ospk,
                   int lsel, long lstride)
{
    const int h = threadIdx.x;
    int l, b;
    if (lsel >= 0) { l = lsel; b = blockIdx.x; }
    else           { l = blockIdx.x >> 8; b = blockIdx.x & 255; }

    const float th = thr[h];
    const float dc = dec[h];
    const float rs = rstv[h];

    float mem = mem0[((long)l * 256 + b) * 128 + h];
    float spk = 0.f;
    float cnt = 0.f;

    const bool last = (l == 3);
    float* __restrict__ om = omem + (long)b * 301 * 128 + h;
    float* __restrict__ os = ospk + (long)b * 301 * 128 + h;
    if (last) { om[0] = mem; os[0] = 0.f; }

    const float* __restrict__ p =
        xs + ((lsel >= 0 ? 0L : (long)l * lstride) + (long)b * TT_) * HID_ + h;

    for (int t0 = 0; t0 < TT_; t0 += 20) {
        float v[20];
#pragma unroll
        for (int j = 0; j < 20; ++j) v[j] = p[(long)(t0 + j) * HID_];
#pragma unroll
        for (int j = 0; j < 20; ++j) {
            mem = rs * spk + mem * dc * (1.f - spk) + v[j];
            spk = (mem - th > 0.f) ? 1.f : 0.f;
            cnt += spk;
            if (last) {
                om[(long)(t0 + j + 1) * 128] = mem;
                os[(long)(t0 + j + 1) * 128] = spk;
            }
        }
    }

    rates[((long)l * 256 + b) * 128 + h] = cnt * (1.f / 300.f);
}

// ---------------------------------------------------------------------------
// Legacy fused drive+scan (fallback when ws is tiny).
// ---------------------------------------------------------------------------
__global__ __launch_bounds__(128, 2)
void k3_fused(const float* __restrict__ inp, const float* __restrict__ Aw,
              const float* __restrict__ Ab, const float* __restrict__ thr,
              const float* __restrict__ dec, const float* __restrict__ rstv,
              const float* __restrict__ mem0, float* __restrict__ rates,
              float* __restrict__ omem, float* __restrict__ ospk)
{
    const int h = threadIdx.x;
    const int l = blockIdx.x & 3;
    const int b = blockIdx.x >> 2;

    float a[128];
#pragma unroll
    for (int k = 0; k < 128; ++k)
        a[k] = Aw[((long)l * 128 + k) * 128 + h];

    const float ab = Ab[l * 128 + h];
    const float th = thr[h];
    const float dc = dec[h];
    const float rs = rstv[h];

    float mem = mem0[((long)l * 256 + b) * 128 + h];
    float spk = 0.f, cnt = 0.f;

    const bool last = (l == 3);
    float* __restrict__ om = omem + (long)b * 301 * 128 + h;
    float* __restrict__ os = ospk + (long)b * 301 * 128 + h;
    if (last) { om[0] = mem; os[0] = 0.f; }

    const float* __restrict__ ip = inp + (long)b * 300 * 128;

    for (int t = 0; t < 300; ++t) {
        float acc = ab;
#pragma unroll
        for (int k = 0; k < 128; ++k)
            acc = fmaf(ip[k], a[k], acc);
        ip += 128;
        mem = rs * spk + mem * dc * (1.f - spk) + acc;
        spk = (mem - th > 0.f) ? 1.f : 0.f;
        cnt += spk;
        if (last) {
            om[(long)(t + 1) * 128] = mem;
            os[(long)(t + 1) * 128] = spk;
        }
    }
    rates[((long)l * 256 + b) * 128 + h] = cnt * (1.f / 300.f);
}

// ---------------------------------------------------------------------------
// K4: head. block per batch row b.
// ---------------------------------------------------------------------------
__global__ __launch_bounds__(256)
void k4_head(const float* __restrict__ rates, const float* __restrict__ fcw,
             const float* __restrict__ fcb, const float* __restrict__ wout,
             const float* __restrict__ bout, float* __restrict__ out)
{
    __shared__ float cat[512];
    const int b = blockIdx.x;
    const int tid = threadIdx.x;

    for (int c = tid; c < 512; c += 256) {
        const int l = c >> 7;
        const int k = c & 127;
        float s = fcb[l * 128 + k];
        const float* __restrict__ rp = rates + ((long)l * 256 + b) * 128;
        const float* __restrict__ wp = fcw + (long)l * 128 * 128 + k;
#pragma unroll 8
        for (int hh = 0; hh < 128; ++hh)
            s = fmaf(rp[hh], wp[(long)hh * 128], s);
        cat[c] = s > 0.f ? s : 0.f;
    }
    __syncthreads();

    if (tid < NOUT_) {
        float s = bout[tid];
#pragma unroll 8
        for (int c = 0; c < 512; ++c)
            s = fmaf(cat[c], wout[(long)c * NOUT_ + tid], s);
        out[(long)b * NOUT_ + tid] = s;
    }
}

// ---------------------------------------------------------------------------
// K5: A_norm = sum |A_w|. Single block.
// ---------------------------------------------------------------------------
__global__ __launch_bounds__(256)
void k5_anorm(const float* __restrict__ Aw, float* __restrict__ out)
{
    __shared__ float red[256];
    const int tid = threadIdx.x;
    float s = 0.f;
    for (int i = tid; i < LL_ * 128 * 128; i += 256)
        s += fabsf(Aw[i]);
    red[tid] = s;
    __syncthreads();
#pragma unroll
    for (int st = 128; st > 0; st >>= 1) {
        if (tid < st) red[tid] += red[tid + st];
        __syncthreads();
    }
    if (tid == 0) out[0] = red[0];
}

// ---------------------------------------------------------------------------
extern "C" void kernel_launch(void* const* d_in, const int* in_sizes, int n_in,
                              void* d_out, int out_size, void* d_ws, size_t ws_size,
                              hipStream_t stream)
{
    const float* x    = (const float*)d_in[0];
    const float* w_in = (const float*)d_in[1];
    const float* b_in = (const float*)d_in[2];
    const float* A_w  = (const float*)d_in[3];
    const float* A_b  = (const float*)d_in[4];
    const float* fc_w = (const float*)d_in[5];
    const float* fc_b = (const float*)d_in[6];
    const float* w_out= (const float*)d_in[7];
    const float* b_out= (const float*)d_in[8];
    const float* thr  = (const float*)d_in[9];
    const float* dec  = (const float*)d_in[10];
    const float* rst  = (const float*)d_in[11];
    const float* mem0 = (const float*)d_in[12];

    float* out = (float*)d_out;
    float* ws  = (float*)d_ws;

    const long INP_ELTS = (long)NROWS_ * HID_;
    const long XS_FULL  = 4L * NROWS_ * HID_;
    const long RATES    = 4L * 256 * 128;

    float* inp = ws;

    // K1: MFMA input projection. 76800/64 = 1200 blocks.
    k1_mfma<<<1200, 256, 0, stream>>>(x, w_in, b_in, inp);

    const size_t need_full = (size_t)(INP_ELTS + XS_FULL + RATES) * 4;
    const size_t need_perl = (size_t)(INP_ELTS + INP_ELTS + RATES) * 4;

    if (ws_size >= need_full) {
        float* xs    = ws + INP_ELTS;
        float* rates = xs + XS_FULL;
        k2_mfma<<<dim3(1200, 4), 256, 0, stream>>>(inp, A_w, A_b, xs, -1, (long)NROWS_);
        k3_scan_split<<<1024, 128, 0, stream>>>(xs, thr, dec, rst, mem0, rates,
                                                out + HMEM_OFF, out + HSPK_OFF,
                                                -1, (long)NROWS_);
        k4_head<<<256, 256, 0, stream>>>(rates, fc_w, fc_b, w_out, b_out, out + OUT_OFF);
    } else if (ws_size >= need_perl) {
        float* xs    = ws + INP_ELTS;
        float* rates = xs + INP_ELTS;
        for (int l = 0; l < 4; ++l) {
            k2_mfma<<<dim3(1200, 1), 256, 0, stream>>>(inp, A_w, A_b, xs, l, 0L);
            k3_scan_split<<<256, 128, 0, stream>>>(xs, thr, dec, rst, mem0, rates,
                                                   out + HMEM_OFF, out + HSPK_OFF,
                                                   l, 0L);
        }
        k4_head<<<256, 256, 0, stream>>>(rates, fc_w, fc_b, w_out, b_out, out + OUT_OFF);
    } else {
        float* rates = ws + INP_ELTS;
        k3_fused<<<1024, 128, 0, stream>>>(inp, A_w, A_b, thr, dec, rst, mem0,
                                           rates, out + HMEM_OFF, out + HSPK_OFF);
        k4_head<<<256, 256, 0, stream>>>(rates, fc_w, fc_b, w_out, b_out, out + OUT_OFF);
    }

    k5_anorm<<<1, 256, 0, stream>>>(A_w, out + ANORM_OFF);
}